// Round 18
// baseline (349.860 us; speedup 1.0000x reference)
//
#include <hip/hip_runtime.h>
#include <hip/hip_bf16.h>
#include <math.h>

// Transformer block. Round 29: attention v11 — concurrent pair streams.
// v10 processed the paired q-tiles (qt, 31-qt) SERIALLY (256 thr, 2
// blocks/CU = 2 waves/SIMD; VALU-bound softmax had no TLP to hide under:
// VALUBusy 50, Mfma 18). The pair shares the same head's K/V with a
// shared tile prefix -> now 512 thr / 8 waves: waves 0-3 = stream A (qt),
// waves 4-7 = stream B (31-qt), ONE K/V staging stream of max(ntk) tiles
// serves both. 16 waves/CU (avg ~2.85 active/SIMD, +42% VALU issue),
// staged tiles 272->200 (-26% FETCH). Stream compute is wave-uniform
// if(t<ntk_me), no barrier inside; staging+barriers all-threads (v9's
// proven commit->sync->prefetch shape). Per-stream softmax/PV bodies
// byte-copied from v10 (chain-broken, defer-max). Epilogue scratch:
// stream s uses Ks[s]. Everything else frozen at R28.
// D_MODEL=1024, N_HEAD=16, D_HEAD=64, EXP=4, B=2, T=2048, EPS=1e-5

#define D_MODEL 1024
#define N_HEAD  16
#define D_HEAD  64
#define SEQ_T   2048
#define BATCH   2
#define NROWS   (BATCH * SEQ_T)   // 4096
#define C3      (3 * D_MODEL)     // 3072
#define D_FF    (4 * D_MODEL)     // 4096

typedef __bf16 bf16x8 __attribute__((ext_vector_type(8)));
typedef __bf16 bf16x4t __attribute__((ext_vector_type(4)));
typedef short  s16x4  __attribute__((ext_vector_type(4)));
typedef float  f32x4  __attribute__((ext_vector_type(4)));

#define WAIT_VM0() asm volatile("s_waitcnt vmcnt(0)" ::: "memory")
#define WAIT_VM2() asm volatile("s_waitcnt vmcnt(2)" ::: "memory")
#define WAIT_VM4() asm volatile("s_waitcnt vmcnt(4)" ::: "memory")
#define WAIT_VM6() asm volatile("s_waitcnt vmcnt(6)" ::: "memory")

// 16x16x16 bf16 MFMA: builtin name differs across ROCm versions.
__device__ __forceinline__ f32x4 mfma16_bf16(s16x4 a, s16x4 b, f32x4 c)
{
#if __has_builtin(__builtin_amdgcn_mfma_f32_16x16x16_bf16)
    return __builtin_amdgcn_mfma_f32_16x16x16_bf16(
        __builtin_bit_cast(bf16x4t, a), __builtin_bit_cast(bf16x4t, b), c, 0, 0, 0);
#else
    return __builtin_amdgcn_mfma_f32_16x16x16bf16_1k(a, b, c, 0, 0, 0);
#endif
}

// ---------------------------------------------------------------- LayerNorm
__global__ __launch_bounds__(256) void ln_kernel(
    const float* __restrict__ in, const float* __restrict__ w,
    const float* __restrict__ b, __hip_bfloat16* __restrict__ out, int D)
{
    const int row = blockIdx.x;
    const int tid = threadIdx.x;
    const float* x = in + (size_t)row * 1024;

    const float4 v = *(const float4*)(x + tid * 4);
    float s  = v.x + v.y + v.z + v.w;
    float s2 = v.x * v.x + v.y * v.y + v.z * v.z + v.w * v.w;

    __shared__ float rs[256], rs2[256];
    rs[tid] = s; rs2[tid] = s2;
    __syncthreads();
    for (int off = 128; off > 0; off >>= 1) {
        if (tid < off) { rs[tid] += rs[tid + off]; rs2[tid] += rs2[tid + off]; }
        __syncthreads();
    }
    const float mu   = rs[0] * (1.0f / 1024.0f);
    const float var  = rs2[0] * (1.0f / 1024.0f) - mu * mu;
    const float rstd = rsqrtf(var + 1e-5f);

    const float4 w4 = *(const float4*)(w + tid * 4);
    const float4 b4 = *(const float4*)(b + tid * 4);
    float o[4] = {(v.x - mu) * rstd * w4.x + b4.x,
                  (v.y - mu) * rstd * w4.y + b4.y,
                  (v.z - mu) * rstd * w4.z + b4.z,
                  (v.w - mu) * rstd * w4.w + b4.w};
    ushort4 pk;
    { __hip_bfloat16 e0 = __float2bfloat16(o[0]); pk.x = *(unsigned short*)&e0;
      __hip_bfloat16 e1 = __float2bfloat16(o[1]); pk.y = *(unsigned short*)&e1;
      __hip_bfloat16 e2 = __float2bfloat16(o[2]); pk.z = *(unsigned short*)&e2;
      __hip_bfloat16 e3 = __float2bfloat16(o[3]); pk.w = *(unsigned short*)&e3; }
    *(ushort4*)(out + (size_t)row * 1024 + tid * 4) = pk;
}

// ---------------- fused prep: weight transposes (blocks 0..12287) + ln1
__global__ __launch_bounds__(256) void prep_kernel(
    const float* __restrict__ attn_w, const float* __restrict__ proj_w,
    const float* __restrict__ fc_w,   const float* __restrict__ fc2_w,
    __hip_bfloat16* __restrict__ attn_wt, __hip_bfloat16* __restrict__ proj_wt,
    __hip_bfloat16* __restrict__ fc_wt,   __hip_bfloat16* __restrict__ fc2_wt,
    const float* __restrict__ x, const float* __restrict__ ln1_w,
    const float* __restrict__ ln1_b, __hip_bfloat16* __restrict__ ln_out)
{
    __shared__ float smem[32 * 33];
    int tb = blockIdx.x;
    const int tid = threadIdx.x;

    if (tb >= 12288) {
        // -------- ln1 path
        const int row = tb - 12288;
        const float* xr = x + (size_t)row * 1024;
        const float4 v = *(const float4*)(xr + tid * 4);
        float s  = v.x + v.y + v.z + v.w;
        float s2 = v.x * v.x + v.y * v.y + v.z * v.z + v.w * v.w;
        float* rs  = smem;
        float* rs2 = smem + 256;
        rs[tid] = s; rs2[tid] = s2;
        __syncthreads();
        for (int off = 128; off > 0; off >>= 1) {
            if (tid < off) { rs[tid] += rs[tid + off]; rs2[tid] += rs2[tid + off]; }
            __syncthreads();
        }
        const float mu   = rs[0] * (1.0f / 1024.0f);
        const float var  = rs2[0] * (1.0f / 1024.0f) - mu * mu;
        const float rstd = rsqrtf(var + 1e-5f);
        const float4 w4 = *(const float4*)(ln1_w + tid * 4);
        const float4 b4 = *(const float4*)(ln1_b + tid * 4);
        float o[4] = {(v.x - mu) * rstd * w4.x + b4.x,
                      (v.y - mu) * rstd * w4.y + b4.y,
                      (v.z - mu) * rstd * w4.z + b4.z,
                      (v.w - mu) * rstd * w4.w + b4.w};
        ushort4 pk;
        { __hip_bfloat16 e0 = __float2bfloat16(o[0]); pk.x = *(unsigned short*)&e0;
          __hip_bfloat16 e1 = __float2bfloat16(o[1]); pk.y = *(unsigned short*)&e1;
          __hip_bfloat16 e2 = __float2bfloat16(o[2]); pk.z = *(unsigned short*)&e2;
          __hip_bfloat16 e3 = __float2bfloat16(o[3]); pk.w = *(unsigned short*)&e3; }
        *(ushort4*)(ln_out + (size_t)row * 1024 + tid * 4) = pk;
        return;
    }

    // -------- transpose path (fp32 [K,N] -> bf16 [N,K])
    float (*t)[33] = (float(*)[33])smem;
    const float* W; __hip_bfloat16* Wt; int K, N;
    if (tb < 3072)      { W = attn_w; Wt = attn_wt; K = D_MODEL; N = C3; }
    else if (tb < 4096) { tb -= 3072; W = proj_w; Wt = proj_wt; K = D_MODEL; N = D_MODEL; }
    else if (tb < 8192) { tb -= 4096; W = fc_w;   Wt = fc_wt;   K = D_MODEL; N = D_FF; }
    else                { tb -= 8192; W = fc2_w;  Wt = fc2_wt;  K = D_FF;    N = D_MODEL; }
    const int ntx = N >> 5;
    const int k0 = (tb / ntx) * 32;
    const int n0 = (tb % ntx) * 32;

    const int row = tid >> 3;        // 0..31
    const int c4  = (tid & 7) * 4;   // 0,4,...,28

    const float4 v = *(const float4*)&W[(size_t)(k0 + row) * N + n0 + c4];
    t[row][c4 + 0] = v.x; t[row][c4 + 1] = v.y;
    t[row][c4 + 2] = v.z; t[row][c4 + 3] = v.w;
    __syncthreads();

    ushort4 pk;
    { __hip_bfloat16 e0 = __float2bfloat16(t[c4 + 0][row]); pk.x = *(unsigned short*)&e0;
      __hip_bfloat16 e1 = __float2bfloat16(t[c4 + 1][row]); pk.y = *(unsigned short*)&e1;
      __hip_bfloat16 e2 = __float2bfloat16(t[c4 + 2][row]); pk.z = *(unsigned short*)&e2;
      __hip_bfloat16 e3 = __float2bfloat16(t[c4 + 3][row]); pk.w = *(unsigned short*)&e3; }
    *(ushort4*)&Wt[(size_t)(n0 + row) * K + k0 + c4] = pk;
}

// ----------------------------------------------------------- helpers
__device__ __forceinline__ void async16(const __hip_bfloat16* g, __hip_bfloat16* l)
{
    __builtin_amdgcn_global_load_lds(
        (const __attribute__((address_space(1))) void*)g,
        (__attribute__((address_space(3))) void*)l, 16, 0, 0);
}

__device__ __forceinline__ float gelu_fast(float v)
{
    const float t = v * (0.7978845608f + 0.0356774081f * v * v);
    return v / (1.0f + exp2f(-2.885390082f * t));
}

// XCD-contiguous work remap (T1). All GEMM (x,y)-grids here are %8 == 0.
__device__ __forceinline__ void swz_xcd(int& bx, int& by)
{
    const int nbx = gridDim.x;
    const int nwg = nbx * gridDim.y;
    int lin = blockIdx.y * nbx + blockIdx.x;
    const int per = nwg >> 3;
    lin = (lin & 7) * per + (lin >> 3);   // XCD x -> contiguous work chunk
    bx = lin % nbx;
    by = lin / nbx;
}

// ================= 8-phase 256x256 core (fc1 + qkv) =======================
// (verified R20-R28; ledger: vmcnt(4)@ph1, vmcnt(2)@ph3, floor 2 in
// flight, drain->barrier->read race-free.)

__device__ __forceinline__ void gemm8p_core(
    const __hip_bfloat16* __restrict__ A,
    const __hip_bfloat16* __restrict__ Bt,
    int K, int row0, int col0, f32x4 (&acc)[8][4],
    __hip_bfloat16 (*Asl)[4][64 * 64], __hip_bfloat16 (*Bsl)[2][128 * 64])
{
    const int tid  = threadIdx.x;
    const int wv   = tid >> 6;
    const int lane = tid & 63;
    const int ln15 = lane & 15;
    const int lq   = lane >> 4;
    const int wr   = wv >> 2;
    const int wc   = wv & 3;

    const int srow = tid >> 3;                          // 0..63
    const int sg   = ((tid & 7) ^ ((tid >> 3) & 7)) * 8;  // inv-swizzled src granule
    const __hip_bfloat16* Ab = A  + (size_t)(row0 + srow) * K + sg;
    const __hip_bfloat16* Bb = Bt + (size_t)(col0 + srow) * K + sg;
    const int nt = K >> 6;

#pragma unroll
    for (int mi = 0; mi < 8; ++mi)
#pragma unroll
        for (int ni = 0; ni < 4; ++ni) acc[mi][ni] = (f32x4){0.f, 0.f, 0.f, 0.f};

    auto stA = [&](int t, int buf, int b) {
        async16(Ab + (size_t)(b * 64) * K + t * 64, &Asl[buf][b][0] + tid * 8);
    };
    auto stB = [&](int t, int buf, int h) {
        async16(Bb + (size_t)(h * 128) * K + t * 64, &Bsl[buf][h][0] + tid * 8);
        async16(Bb + (size_t)(h * 128 + 64) * K + t * 64,
                &Bsl[buf][h][0] + 4096 + tid * 8);
    };

    const int rg0 = (lq ^ (ln15 & 7)) * 8;          // kk=0 read granule (elems)
    const int rg1 = ((4 | lq) ^ (ln15 & 7)) * 8;    // kk=1
    auto ldA = [&](int buf, int mi, int kk) -> bf16x8 {
        return *(const bf16x8*)&Asl[buf][wr * 2 + (mi >> 2)]
            [((mi & 3) * 16 + ln15) * 64 + (kk ? rg1 : rg0)];
    };
    auto ldB = [&](int buf, int ni, int kk) -> bf16x8 {
        return *(const bf16x8*)&Bsl[buf][wc >> 1]
            [((wc & 1) * 64 + ni * 16 + ln15) * 64 + (kk ? rg1 : rg0)];
    };

    // prologue: all of tile 0 -> buf 0 (8 loads), drain, join.
    stB(0, 0, 0); stB(0, 0, 1);
    stA(0, 0, 0); stA(0, 0, 2); stA(0, 0, 1); stA(0, 0, 3);
    WAIT_VM0();
    __builtin_amdgcn_s_barrier();

    for (int t = 0; t < nt; ++t) {
        const int pp = t & 1, op = pp ^ 1;
        const int tc = (t + 1 < nt) ? t + 1 : nt - 1;
        bf16x8 af[2][2], bfr[4][2];

        // -------- phase 0: mi 0,1 (+ all B fragment reads, held in regs)
#pragma unroll
        for (int m = 0; m < 2; ++m) { af[m][0] = ldA(pp, m, 0); af[m][1] = ldA(pp, m, 1); }
#pragma unroll
        for (int ni = 0; ni < 4; ++ni) { bfr[ni][0] = ldB(pp, ni, 0); bfr[ni][1] = ldB(pp, ni, 1); }
        stB(tc, op, 0);
        __builtin_amdgcn_s_barrier();
        __builtin_amdgcn_s_setprio(1);
#pragma unroll
        for (int kk = 0; kk < 2; ++kk)
#pragma unroll
            for (int m = 0; m < 2; ++m)
#pragma unroll
                for (int ni = 0; ni < 4; ++ni)
                    acc[m][ni] = __builtin_amdgcn_mfma_f32_16x16x32_bf16(
                        af[m][kk], bfr[ni][kk], acc[m][ni], 0, 0, 0);
        __builtin_amdgcn_s_setprio(0);
        __builtin_amdgcn_s_barrier();

        // -------- phase 1: mi 2,3
#pragma unroll
        for (int m = 0; m < 2; ++m) { af[m][0] = ldA(pp, 2 + m, 0); af[m][1] = ldA(pp, 2 + m, 1); }
        stB(tc, op, 1);
        WAIT_VM4();
        __builtin_amdgcn_s_barrier();
        __builtin_amdgcn_s_setprio(1);
#pragma unroll
        for (int kk = 0; kk < 2; ++kk)
#pragma unroll
            for (int m = 0; m < 2; ++m)
#pragma unroll
                for (int ni = 0; ni < 4; ++ni)
                    acc[2 + m][ni] = __builtin_amdgcn_mfma_f32_16x16x32_bf16(
                        af[m][kk], bfr[ni][kk], acc[2 + m][ni], 0, 0, 0);
        __builtin_amdgcn_s_setprio(0);
        __builtin_amdgcn_s_barrier();

        // -------- phase 2: mi 4,5
#pragma unroll
        for (int m = 0; m < 2; ++m) { af[m][0] = ldA(pp, 4 + m, 0); af[m][1] = ldA(pp, 4 + m, 1); }
        stA(tc, op, 0); stA(tc, op, 2);
        __builtin_amdgcn_s_barrier();
        __builtin_amdgcn_s_setprio(1);
#pragma unroll
        for (int kk = 0; kk < 2; ++kk)
#pragma unroll
            for (int m = 0; m < 2; ++m)
#pragma unroll
                for (int ni = 0; ni < 4; ++ni)
                    acc[4 + m][ni] = __builtin_amdgcn_mfma_f32_16x16x32_bf16(
                        af[m][kk], bfr[ni][kk], acc[4 + m][ni], 0, 0, 0);
        __builtin_amdgcn_s_setprio(0);
        __builtin_amdgcn_s_barrier();

        // -------- phase 3: mi 6,7
#pragma unroll
        for (int m = 0; m < 2; ++m) { af[m][0] = ldA(pp, 6 + m, 0); af[m][1] = ldA(pp, 6 + m, 1); }
        stA(tc, op, 1); stA(tc, op, 3);
        WAIT_VM2();
        __builtin_amdgcn_s_barrier();
        __builtin_amdgcn_s_setprio(1);
#pragma unroll
        for (int kk = 0; kk < 2; ++kk)
#pragma unroll
            for (int m = 0; m < 2; ++m)
#pragma unroll
                for (int ni = 0; ni < 4; ++ni)
                    acc[6 + m][ni] = __builtin_amdgcn_mfma_f32_16x16x32_bf16(
                        af[m][kk], bfr[ni][kk], acc[6 + m][ni], 0, 0, 0);
        __builtin_amdgcn_s_setprio(0);
        __builtin_amdgcn_s_barrier();
    }
}

// ---------------- fc1 kernel (8-phase 256x256, bias+gelu, bf16 out)
__global__ __launch_bounds__(512, 1) void gemm8p_kernel(
    const __hip_bfloat16* __restrict__ A,   // [M,K]
    const __hip_bfloat16* __restrict__ Bt,  // [N,K]
    const float* __restrict__ bias,         // [N]
    __hip_bfloat16* __restrict__ Cout,      // [M,N] bf16
    int M, int N, int K, int act)
{
    __shared__ __align__(16) __hip_bfloat16 Asl[2][4][64 * 64];
    __shared__ __align__(16) __hip_bfloat16 Bsl[2][2][128 * 64];

    int bx, by;
    swz_xcd(bx, by);
    const int row0 = by * 256;
    const int col0 = bx * 256;

    f32x4 acc[8][4];
    gemm8p_core(A, Bt, K, row0, col0, acc, Asl, Bsl);

    const int tid  = threadIdx.x;
    const int wv   = tid >> 6;
    const int lane = tid & 63;
    const int ln15 = lane & 15;
    const int lq   = lane >> 4;
    const int mbase = (wv >> 2) * 128;
    const int nbase = (wv & 3) * 64;

#pragma unroll
    for (int mi = 0; mi < 8; ++mi) {
#pragma unroll
        for (int ni = 0; ni < 4; ++ni) {
            const int gc = col0 + nbase + ni * 16 + ln15;
            const float bv = bias[gc];
#pragma unroll
            for (int r = 0; r < 4; ++r) {
                const int gr = row0 + mbase + mi * 16 + lq * 4 + r;
                float v = acc[mi][ni][r] + bv;
                if (act == 1) v = gelu_fast(v);
                Cout[(size_t)gr * N + gc] = __float2bfloat16(v);
            }
        }
    }
}

// ---------------- qkv kernel (8-phase 256x256) with routing epilogue
__global__ __launch_bounds__(512, 1) void qkv8p_kernel(
    const __hip_bfloat16* __restrict__ A,
    const __hip_bfloat16* __restrict__ Bt,
    const float* __restrict__ bias,
    __hip_bfloat16* __restrict__ Qb,
    __hip_bfloat16* __restrict__ Kb,
    __hip_bfloat16* __restrict__ Vtb)
{
    __shared__ __align__(16) __hip_bfloat16 Asl[2][4][64 * 64];
    __shared__ __align__(16) __hip_bfloat16 Bsl[2][2][128 * 64];

    int bx, by;
    swz_xcd(bx, by);
    const int row0 = by * 256;
    const int col0 = bx * 256;

    f32x4 acc[8][4];
    gemm8p_core(A, Bt, D_MODEL, row0, col0, acc, Asl, Bsl);

    const int tid  = threadIdx.x;
    const int wv   = tid >> 6;
    const int lane = tid & 63;
    const int ln15 = lane & 15;
    const int lq   = lane >> 4;
    const int mbase = (wv >> 2) * 128;
    const int nbase = (wv & 3) * 64;

#pragma unroll
    for (int mi = 0; mi < 8; ++mi) {
        const int gr0 = row0 + mbase + mi * 16 + lq * 4;   // + r
        const int bb  = gr0 >> 11;
        const int q0  = gr0 & 2047;
#pragma unroll
        for (int ni = 0; ni < 4; ++ni) {
            const int gc  = col0 + nbase + ni * 16 + ln15;
            const float bv = bias[gc];
            const int sec = gc >> 10;            // 0:Q 1:K 2:V
            const int hd  = (gc & 1023) >> 6;
            const int d   = gc & 63;
            if (sec == 2) {
                unsigned short u[4];
#pragma unroll
                for (int r = 0; r < 4; ++r) {
                    __hip_bfloat16 e = __float2bfloat16(acc[mi][ni][r] + bv);
                    u[r] = *(unsigned short*)&e;
                }
                uint2 pk;
                pk.x = (unsigned int)u[0] | ((unsigned int)u[1] << 16);
                pk.y = (unsigned int)u[2] | ((unsigned int)u[3] << 16);
                *(uint2*)(Vtb + ((size_t)((bb * N_HEAD + hd) * D_HEAD + d)) * SEQ_T + q0) = pk;
            } else {
                __hip_bfloat16* dst = (sec == 0 ? Qb : Kb)
                    + ((size_t)((bb * N_HEAD + hd) * SEQ_T + q0)) * D_HEAD + d;
#pragma unroll
                for (int r = 0; r < 4; ++r)
                    dst[(size_t)r * D_HEAD] = __float2bfloat16(acc[mi][ni][r] + bv);
            }
        }
    }
}

// ============== GEMM core B: 64x128 tile, BK=64, 3-slot rotation =========
// (verified R27: vmcnt(6) counted drain, 2-tile lead, race-free)
__device__ __forceinline__ void stage_db2w(
    const __hip_bfloat16* __restrict__ Ab, const __hip_bfloat16* __restrict__ Bb,
    int K, int kt, __hip_bfloat16* __restrict__ as,
    __hip_bfloat16* __restrict__ bs, int tid)
{
    const int k0 = kt * 64;
#pragma unroll
    for (int s = 0; s < 2; ++s) {
        async16(Ab + k0 + s * 32, as + s * 64 * 32 + tid * 8);
#pragma unroll
        for (int i = 0; i < 2; ++i)
            async16(Bb + (size_t)(i * 64) * K + k0 + s * 32,
                    bs + s * 128 * 32 + i * 64 * 32 + tid * 8);
    }
}

__device__ __forceinline__ void gemm_db2w(
    const __hip_bfloat16* __restrict__ A,
    const __hip_bfloat16* __restrict__ Bt,
    int K, int row0, int col0, f32x4 (&acc)[2][4])
{
    __shared__ __align__(16) __hip_bfloat16 Asl[3][2 * 64 * 32];    // 24KB
    __shared__ __align__(16) __hip_bfloat16 Bsl[3][2 * 128 * 32];   // 48KB

    const int tid  = threadIdx.x;
    const int wv   = tid >> 6;
    const int lane = tid & 63;
    const int ln15 = lane & 15;
    const int lq   = lane >> 4;
    const int mbase = (wv >> 1) * 32;
    const int nbase = (wv & 1) * 64;
    const int rcol = (lq ^ ((ln15 >> 1) & 3)) * 8;
    const int ssw  = ((tid & 3) ^ ((tid >> 3) & 3)) * 8;
    const __hip_bfloat16* Ab = A  + (size_t)(row0 + (tid >> 2)) * K + ssw;
    const __hip_bfloat16* Bb = Bt + (size_t)(col0 + (tid >> 2)) * K + ssw;
    const int nt = K >> 6;

#pragma unroll
    for (int mi = 0; mi < 2; ++mi)
#pragma unroll
        for (int ni = 0; ni < 4; ++ni) acc[mi][ni] = (f32x4){0.f, 0.f, 0.f, 0.f};

    // prologue: tiles 0,1 -> slots 0,1 (12 loads); drain tile 0; join.
    stage_db2w(Ab, Bb, K, 0, &Asl[0][0], &Bsl[0][0], tid);
    stage_db2w(Ab, Bb, K, 1, &Asl[1][0], &Bsl[1][0], tid);
    WAIT_VM6();
    __builtin_amdgcn_s_barrier();

    for (int t = 0; t < nt; ++t) {
        const int p   = t % 3;
        const int p2  = (t + 2) % 3;
        const int tcl = (t + 2 < nt) ? t + 2 : nt - 1;
        bf16x8 af[2][2], bfr[2][4];

#pragma unroll
        for (int s = 0; s < 2; ++s) {
#pragma unroll
            for (int mi = 0; mi < 2; ++mi)
                af[s][mi] = *(const bf16x8*)
                    &Asl[p][s * 64 * 32 + (mbase + mi * 16 + ln15) * 32 + rcol];
#pragma unroll
            for (int ni = 0; ni < 4; ++ni)
                bfr[s][ni] = *(const bf16x8*)
                    &Bsl[p][s * 128 * 32 + (nbase + ni * 16 + ln15) * 32 + rcol];
        }

        stage_db2w(Ab, Bb, K, tcl, &Asl[p2][0], &Bsl[p2][0], tid);

        WAIT_VM6();                     // drain tile t+1; t+2 stays in flight
        __builtin_amdgcn_s_barrier();   // all waves: tile t+1 ready

        __builtin_amdgcn_s_setprio(1);
#pragma unroll
        for (int s = 0; s < 2; ++s)
#pragma unroll
            for (int mi = 0; mi < 2; ++mi)
#pragma unroll
                for (int ni = 0; ni < 4; ++ni)
                    acc[mi][ni] = __builtin_amdgcn_mfma_f32_16x16x32_bf16(
                        af[s][mi], bfr[s][ni], acc[mi][ni], 0, 0, 0);
        __builtin_amdgcn_s_setprio(0);
    }
}

// ---------------- 64x128 BK=64 kernel (proj, fc2)
__global__ __launch_bounds__(256, 2) void gemm64_kernel(
    const __hip_bfloat16* __restrict__ A,
    const __hip_bfloat16* __restrict__ Bt,
    const float* __restrict__ bias,
    const float* __restrict__ residual,
    void* __restrict__ Cout,
    int M, int N, int K, int act, int outBf16)
{
    int bx, by;
    swz_xcd(bx, by);
    const int row0 = by * 64;
    const int col0 = bx * 128;

    f32x4 acc[2][4];
    gemm_db2w(A, Bt, K, row0, col0, acc);

    const int tid  = threadIdx.x;
    const int wv   = tid >> 6;
    const int lane = tid & 63;
    const int ln15 = lane & 15;
    const int lq   = lane >> 4;
    const int mbase = (wv >> 1) * 32;
    const int nbase = (wv & 1) * 64;

#pragma unroll
    for (int mi = 0; mi < 2; ++mi) {
#pragma unroll
        for (int ni = 0; ni < 4; ++ni) {
            const int gc = col0 + nbase + ni * 16 + ln15;
            const float bv = bias[gc];
#pragma unroll
            for (int r = 0; r < 4; ++r) {
                const int gr = row0 + mbase + mi * 16 + lq * 4 + r;
                float v = acc[mi][ni][r] + bv;
                if (act == 1) v = gelu_fast(v);
                if (residual) v += residual[(size_t)gr * N + gc];
                if (outBf16)
                    ((__hip_bfloat16*)Cout)[(size_t)gr * N + gc] = __float2bfloat16(v);
                else
                    ((float*)Cout)[(size_t)gr * N + gc] = v;
            }
        }
    }
}

// ------------------------------------------------ MFMA flash attention v11
// 512 threads / 8 waves: waves 0-3 = stream A (qt=pair), waves 4-7 =
// stream B (qt=31-pair). ONE K/V staging stream of ntkB tiles serves both
// (shared prefix). Stream compute is wave-uniform if(t<ntk_me); staging +
// barriers are all-threads (v9 commit->sync->prefetch shape). Per-stream
// softmax (chain-broken, defer-max) and PV identical to v10. Epilogue:
// stream s transposes O through Ks[s].
#define ATQ 64
#define ATK 128
#define NQT (SEQ_T / ATQ)   // 32
#define VP2 136             // Vts row stride (elems)

__global__ __launch_bounds__(512, 2) void mfma_attn_kernel(
    const __hip_bfloat16* __restrict__ Qb,
    const __hip_bfloat16* __restrict__ Kb,
    const __hip_bfloat16* __restrict__ Vtb,
    __hip_bfloat16* __restrict__ y)
{
    __shared__ __align__(16) __hip_bfloat16 Ks[2][ATK * 64];    // [buf][j][d] swz; scratch at end
    __shared__ __align__(16) __hip_bfloat16 Vts[2][D_HEAD * VP2];

    const int flat = (blockIdx.z * gridDim.y + blockIdx.y) * gridDim.x + blockIdx.x;
    const int xcd  = flat & 7;
    const int slot = flat >> 3;
    const int pair = slot & 15;          // 0..15
    const int hb   = slot >> 4;          // 0..3
    const int h    = xcd + 8 * (hb & 1);
    const int b    = hb >> 1;

    const int tid  = threadIdx.x;        // 0..511
    const int wq   = tid >> 8;           // stream: 0 = A (qt=pair), 1 = B
    const int wv4  = (tid >> 6) & 3;     // wave within stream
    const int lane = tid & 63;
    const int ln15 = lane & 15;
    const int lq   = lane >> 4;

    const __hip_bfloat16* Qh = Qb  + (size_t)(b * N_HEAD + h) * SEQ_T * D_HEAD;
    const __hip_bfloat16* Kh = Kb  + (size_t)(b * N_HEAD + h) * SEQ_T * D_HEAD;
    const __hip_bfloat16* Vh = Vtb + (size_t)(b * N_HEAD + h) * D_HEAD * SEQ_T;
    const size_t bT = (size_t)b * SEQ_T;

    const float CEXP = 0.18033688011f;   // 0.125 * log2(e)
    const float DTHR = 8.0f / CEXP;      // defer-max threshold, raw-score units

    // ---- per-stream q-tile
    const int qt_me  = (wq == 0) ? pair : (NQT - 1 - pair);
    const int qbase  = qt_me * ATQ;
    const int ntk_me = (qt_me >> 1) + 1;
    const int ntkMax = ((NQT - 1 - pair) >> 1) + 1;     // B is always larger
    const int qg     = qbase + wv4 * 16 + ln15;         // stats-owner q row

    // K staging (512 thr, 2 gloads): row = (tid>>3) + i*64, granule tid&7.
    const int ksg = ((tid & 7) ^ ((tid >> 3) & 7)) * 8;  // inv-swizzled src granule
    // V staging (512 thr, 2 reg chunks): row = (tid>>4) + i*32, gran tid&15.
    bf16x8 vreg[2];
    const int vr = tid >> 4, vc = tid & 15;

    auto issueK = [&](int kb, int buf) {
#pragma unroll
        for (int i = 0; i < 2; ++i)
            async16(Kh + (size_t)(kb + (tid >> 3) + i * 64) * D_HEAD + ksg,
                    &Ks[buf][i * 4096] + tid * 8);
    };
    auto issueV = [&](int kb) {
#pragma unroll
        for (int i = 0; i < 2; ++i)
            vreg[i] = *(const bf16x8*)(Vh + (size_t)(vr + i * 32) * SEQ_T + kb + vc * 8);
    };
    auto commitV = [&](int buf) {
#pragma unroll
        for (int i = 0; i < 2; ++i)
            *(bf16x8*)&Vts[buf][(vr + i * 32) * VP2 + vc * 8] = vreg[i];
    };

    // QK^T read granules (gemm8p pattern; row = jf*16+ln15)
    const int rg0 = (lq ^ (ln15 & 7)) * 8;
    const int rg1 = ((4 | lq) ^ (ln15 & 7)) * 8;

    bf16x8 qf[2];
#pragma unroll
    for (int kc = 0; kc < 2; ++kc)
        qf[kc] = *(const bf16x8*)(Qh + (size_t)(qbase + wv4 * 16 + ln15) * D_HEAD
                                  + kc * 32 + lq * 8);

    f32x4 Oacc[4];
#pragma unroll
    for (int dn = 0; dn < 4; ++dn) Oacc[dn] = (f32x4){0.f, 0.f, 0.f, 0.f};
    float m_run = -INFINITY, l_run = 0.f;

    issueK(0, 0);     // K gloads FIRST (so V's drain covers them)
    issueV(0);

    for (int t = 0; t < ntkMax; ++t) {
        const int kb  = t * ATK;
        const int buf = t & 1;
        commitV(buf);               // implicit vmcnt wait drains V(t)+K(t)
        __syncthreads();            // all waves' tile-t data in LDS
        if (t + 1 < ntkMax) {       // prefetch t+1 under compute of t
            issueK((t + 1) * ATK, buf ^ 1);
            issueV((t + 1) * ATK);
        }

        if (t < ntk_me) {           // wave-uniform; no barrier inside
            // ---- S^T[j=128][q=16] : A=K (rows j), B=Q (rows q), 16x16x32
            f32x4 st[8];
#pragma unroll
            for (int jf = 0; jf < 8; ++jf) st[jf] = (f32x4){0.f, 0.f, 0.f, 0.f};
            __builtin_amdgcn_s_setprio(1);
#pragma unroll
            for (int jf = 0; jf < 8; ++jf) {
                const int rw = jf * 16 + ln15;
                const bf16x8 kf0 = *(const bf16x8*)&Ks[buf][rw * 64 + rg0];
                const bf16x8 kf1 = *(const bf16x8*)&Ks[buf][rw * 64 + rg1];
                st[jf] = __builtin_amdgcn_mfma_f32_16x16x32_bf16(kf0, qf[0], st[jf], 0, 0, 0);
                st[jf] = __builtin_amdgcn_mfma_f32_16x16x32_bf16(kf1, qf[1], st[jf], 0, 0, 0);
            }
            __builtin_amdgcn_s_setprio(0);

            // ---- causal mask on the diagonal tile (raw-score domain)
            if (t == ntk_me - 1) {
#pragma unroll
                for (int jf = 0; jf < 8; ++jf)
#pragma unroll
                    for (int r = 0; r < 4; ++r)
                        if ((kb + jf * 16 + lq * 4 + r) > qg) st[jf][r] = -INFINITY;
            }

            // ---- online softmax; 4 parallel per-r chains (latency break)
            float tm0 = st[0][0], tm1 = st[0][1], tm2 = st[0][2], tm3 = st[0][3];
#pragma unroll
            for (int jf = 1; jf < 8; ++jf) {
                tm0 = fmaxf(tm0, st[jf][0]);
                tm1 = fmaxf(tm1, st[jf][1]);
                tm2 = fmaxf(tm2, st[jf][2]);
                tm3 = fmaxf(tm3, st[jf][3]);
            }
            float tmax = fmaxf(fmaxf(tm0, tm1), fmaxf(tm2, tm3));
            tmax = fmaxf(tmax, __shfl_xor(tmax, 16));
            tmax = fmaxf(tmax, __shfl_xor(tmax, 32));

            if (!__all(tmax <= m_run + DTHR)) {
                const float mnew  = fmaxf(m_run, tmax);
                const float alpha = exp2f((m_run - mnew) * CEXP);
                l_run *= alpha;
                m_run = mnew;
                float a4[4];
#pragma unroll
                for (int r = 0; r < 4; ++r) a4[r] = __shfl(alpha, lq * 4 + r);
#pragma unroll
                for (int dn = 0; dn < 4; ++dn)
#pragma unroll
                    for (int r = 0; r < 4; ++r) Oacc[dn][r] *= a4[r];
            }
            const float mc = m_run * CEXP;
            float ps0 = 0.f, ps1 = 0.f, ps2 = 0.f, ps3 = 0.f;
#pragma unroll
            for (int jf = 0; jf < 8; ++jf) {
                const float p0 = exp2f(fmaf(st[jf][0], CEXP, -mc));
                const float p1 = exp2f(fmaf(st[jf][1], CEXP, -mc));
                const float p2 = exp2f(fmaf(st[jf][2], CEXP, -mc));
                const float p3 = exp2f(fmaf(st[jf][3], CEXP, -mc));
                st[jf][0] = p0; st[jf][1] = p1; st[jf][2] = p2; st[jf][3] = p3;
                ps0 += p0; ps1 += p1; ps2 += p2; ps3 += p3;
            }
            float psum = (ps0 + ps1) + (ps2 + ps3);
            psum += __shfl_xor(psum, 16);
            psum += __shfl_xor(psum, 32);
            l_run += psum;

            // ---- O += P V via 16x16x16: P-frag is the S^T C-fragment
            __builtin_amdgcn_s_setprio(1);
#pragma unroll
            for (int jf = 0; jf < 8; ++jf) {
                s16x4 pfr;
#pragma unroll
                for (int s = 0; s < 4; ++s) {
                    __hip_bfloat16 e = __float2bfloat16(st[jf][s]);
                    pfr[s] = __builtin_bit_cast(short, e);
                }
#pragma unroll
                for (int dn = 0; dn < 4; ++dn) {
                    const s16x4 vfr = *(const s16x4*)&Vts[buf][(dn * 16 + ln15) * VP2
                                                            + jf * 16 + lq * 4];
                    Oacc[dn] = mfma16_bf16(pfr, vfr, Oacc[dn]);
                }
            }
            __builtin_amdgcn_s_setprio(0);
        }
        // no trailing barrier: next iter's writes target the other buffer,
        // whose reads completed before THIS iter's barrier.
    }

    // ---- epilogue: stream s transposes O through Ks[s] scratch.
    __syncthreads();                    // all compute reads done
    float il[4];
#pragma unroll
    for (int r = 0; r < 4; ++r) il[r] = 1.0f / __shfl(l_run, lq * 4 + r);
#pragma unroll
    for (int dn = 0; dn < 4; ++dn)
#pragma unroll
        for (int r = 0; r < 4; ++r)
            Ks[wq][(wv4 * 16 + lq * 4 + r) * 72 + dn * 16 + ln15] =
                __float2bfloat16(Oacc[dn][r] * il[r]);
    __syncthreads();
    const int r2 = lane >> 3, c8 = (lane & 7) * 8;
#pragma unroll
    for (int i = 0; i < 2; ++i) {
        const int row = wv4 * 16 + r2 + 8 * i;
        const bf16x8 val = *(const bf16x8*)&Ks[wq][row * 72 + c8];
        *(bf16x8*)(y + (bT + qbase + row) * D_MODEL + h * D_HEAD + c8) = val;
    }
}

// ------------------------------------------------------------------ launch
extern "C" void kernel_launch(void* const* d_in, const int* in_sizes, int n_in,
                              void* d_out, int out_size, void* d_ws, size_t ws_size,
                              hipStream_t stream)
{
    const float* x      = (const float*)d_in[0];
    const float* ln1_w  = (const float*)d_in[1];
    const float* ln1_b  = (const float*)d_in[2];
    const float* attn_w = (const float*)d_in[3];
    const float* attn_b = (const float*)d_in[4];
    const float* proj_w = (const float*)d_in[5];
    const float* proj_b = (const float*)d_in[6];
    const float* ln2_w  = (const float*)d_in[7];
    const float* ln2_b  = (const float*)d_in[8];
    const float* fc_w   = (const float*)d_in[9];
    const float* fc_b   = (const float*)d_in[10];
    const float* fc2_w  = (const float*)d_in[11];
    const float* fc2_b  = (const float*)d_in[12];
    float* out = (float*)d_out;

    char* ws = (char*)d_ws;
    __hip_bfloat16* Qb      = (__hip_bfloat16*)(ws);
    __hip_bfloat16* Kb      = (__hip_bfloat16*)(ws + (size_t)8  * 1024 * 1024);
    __hip_bfloat16* Vtb     = (__hip_bfloat16*)(ws + (size_t)16 * 1024 * 1024);
    __hip_bfloat16* h_bf    = (__hip_bfloat16*)(ws);
    __hip_bfloat16* ln_buf  = (__hip_bfloat16*)(ws + (size_t)32 * 1024 * 1024);
    __hip_bfloat16* y_buf   = (__hip_bfloat16*)(ws + (size_t)40 * 1024 * 1024);
    float*          xmid    = (float*)(ws + (size_t)48 * 1024 * 1024);
    __hip_bfloat16* attn_wt = (__hip_bfloat16*)(ws + (size_t)64 * 1024 * 1024);
    __hip_bfloat16* proj_wt = (__hip_bfloat16*)(ws + (size_t)70 * 1024 * 1024);
    __hip_bfloat16* fc_wt   = (__hip_bfloat16*)(ws + (size_t)72 * 1024 * 1024);
    __hip_bfloat16* fc2_wt  = (__hip_bfloat16*)(ws + (size_t)80 * 1024 * 1024);

    dim3 blk256(256);
    dim3 blk512(512);

    // 0. fused prep: all weight transposes + ln1(x) in one launch
    prep_kernel<<<dim3(12288 + NROWS), blk256, 0, stream>>>(
        attn_w, proj_w, fc_w, fc2_w, attn_wt, proj_wt, fc_wt, fc2_wt,
        x, ln1_w, ln1_b, ln_buf);

    // 1. qkv GEMM (8-phase 256x256) -> Qb/Kb/Vtb   grid 12x16 = 192
    qkv8p_kernel<<<dim3(C3 / 256, NROWS / 256), blk512, 0, stream>>>(
        ln_buf, attn_wt, attn_b, Qb, Kb, Vtb);

    // 2. MFMA flash attention v11 (dual-stream pairs) -> y_buf (bf16)
    mfma_attn_kernel<<<dim3(NQT / 2, N_HEAD, BATCH), blk512, 0, stream>>>(
        Qb, Kb, Vtb, y_buf);

    // 3. xmid = x + y_buf @ proj_w + proj_b  (fp32, 3-slot 64x128, grid 512)
    gemm64_kernel<<<dim3(D_MODEL / 128, NROWS / 64), blk256, 0, stream>>>(
        y_buf, proj_wt, proj_b, x, xmid, NROWS, D_MODEL, D_MODEL, 0, 0);

    // 4. ln2(xmid) -> ln_buf (bf16)
    ln_kernel<<<dim3(NROWS), blk256, 0, stream>>>(xmid, ln2_w, ln2_b, ln_buf, D_MODEL);

    // 5. h = gelu(ln_buf @ fc_w + fc_b) -> bf16 (8-phase 256x256, grid 256)
    gemm8p_kernel<<<dim3(D_FF / 256, NROWS / 256), blk512, 0, stream>>>(
        ln_buf, fc_wt, fc_b, h_bf, NROWS, D_FF, D_MODEL, 1);

    // 6. out = xmid + h @ fc2_w + fc2_b  (fp32, 3-slot 64x128, grid 512)
    gemm64_kernel<<<dim3(D_MODEL / 128, NROWS / 64), blk256, 0, stream>>>(
        h_bf, fc2_wt, fc2_b, xmid, out, NROWS, D_MODEL, D_FF, 0, 0);
}

// Round 19
// 334.481 us; speedup vs baseline: 1.0460x; 1.0460x over previous
//
#include <hip/hip_runtime.h>
#include <hip/hip_bf16.h>
#include <math.h>

// Transformer block. Round 30 (final): byte-identical restore of R28, the
// session optimum (335.1 µs; baseline was 520.7). R29's dual-stream attn
// regressed (barrier-synced idle waves are ballast, not TLP) — reverted.
// Composition: fused prep (transpose+ln1); qkv/fc1 on 8-phase 256x256
// counted-vmcnt core; attention v10 (paired, head-locality XCD remap,
// K via global_load_lds w/ verified swizzle, defer-max, chain-broken
// softmax); proj/fc2 on 3-slot counted-vmcnt 64x128 core; vectorized ln2.
// D_MODEL=1024, N_HEAD=16, D_HEAD=64, EXP=4, B=2, T=2048, EPS=1e-5

#define D_MODEL 1024
#define N_HEAD  16
#define D_HEAD  64
#define SEQ_T   2048
#define BATCH   2
#define NROWS   (BATCH * SEQ_T)   // 4096
#define C3      (3 * D_MODEL)     // 3072
#define D_FF    (4 * D_MODEL)     // 4096

typedef __bf16 bf16x8 __attribute__((ext_vector_type(8)));
typedef __bf16 bf16x4t __attribute__((ext_vector_type(4)));
typedef short  s16x4  __attribute__((ext_vector_type(4)));
typedef float  f32x4  __attribute__((ext_vector_type(4)));

#define WAIT_VM0() asm volatile("s_waitcnt vmcnt(0)" ::: "memory")
#define WAIT_VM2() asm volatile("s_waitcnt vmcnt(2)" ::: "memory")
#define WAIT_VM4() asm volatile("s_waitcnt vmcnt(4)" ::: "memory")
#define WAIT_VM6() asm volatile("s_waitcnt vmcnt(6)" ::: "memory")

// 16x16x16 bf16 MFMA: builtin name differs across ROCm versions.
__device__ __forceinline__ f32x4 mfma16_bf16(s16x4 a, s16x4 b, f32x4 c)
{
#if __has_builtin(__builtin_amdgcn_mfma_f32_16x16x16_bf16)
    return __builtin_amdgcn_mfma_f32_16x16x16_bf16(
        __builtin_bit_cast(bf16x4t, a), __builtin_bit_cast(bf16x4t, b), c, 0, 0, 0);
#else
    return __builtin_amdgcn_mfma_f32_16x16x16bf16_1k(a, b, c, 0, 0, 0);
#endif
}

// ---------------------------------------------------------------- LayerNorm
__global__ __launch_bounds__(256) void ln_kernel(
    const float* __restrict__ in, const float* __restrict__ w,
    const float* __restrict__ b, __hip_bfloat16* __restrict__ out, int D)
{
    const int row = blockIdx.x;
    const int tid = threadIdx.x;
    const float* x = in + (size_t)row * 1024;

    const float4 v = *(const float4*)(x + tid * 4);
    float s  = v.x + v.y + v.z + v.w;
    float s2 = v.x * v.x + v.y * v.y + v.z * v.z + v.w * v.w;

    __shared__ float rs[256], rs2[256];
    rs[tid] = s; rs2[tid] = s2;
    __syncthreads();
    for (int off = 128; off > 0; off >>= 1) {
        if (tid < off) { rs[tid] += rs[tid + off]; rs2[tid] += rs2[tid + off]; }
        __syncthreads();
    }
    const float mu   = rs[0] * (1.0f / 1024.0f);
    const float var  = rs2[0] * (1.0f / 1024.0f) - mu * mu;
    const float rstd = rsqrtf(var + 1e-5f);

    const float4 w4 = *(const float4*)(w + tid * 4);
    const float4 b4 = *(const float4*)(b + tid * 4);
    float o[4] = {(v.x - mu) * rstd * w4.x + b4.x,
                  (v.y - mu) * rstd * w4.y + b4.y,
                  (v.z - mu) * rstd * w4.z + b4.z,
                  (v.w - mu) * rstd * w4.w + b4.w};
    ushort4 pk;
    { __hip_bfloat16 e0 = __float2bfloat16(o[0]); pk.x = *(unsigned short*)&e0;
      __hip_bfloat16 e1 = __float2bfloat16(o[1]); pk.y = *(unsigned short*)&e1;
      __hip_bfloat16 e2 = __float2bfloat16(o[2]); pk.z = *(unsigned short*)&e2;
      __hip_bfloat16 e3 = __float2bfloat16(o[3]); pk.w = *(unsigned short*)&e3; }
    *(ushort4*)(out + (size_t)row * 1024 + tid * 4) = pk;
}

// ---------------- fused prep: weight transposes (blocks 0..12287) + ln1
__global__ __launch_bounds__(256) void prep_kernel(
    const float* __restrict__ attn_w, const float* __restrict__ proj_w,
    const float* __restrict__ fc_w,   const float* __restrict__ fc2_w,
    __hip_bfloat16* __restrict__ attn_wt, __hip_bfloat16* __restrict__ proj_wt,
    __hip_bfloat16* __restrict__ fc_wt,   __hip_bfloat16* __restrict__ fc2_wt,
    const float* __restrict__ x, const float* __restrict__ ln1_w,
    const float* __restrict__ ln1_b, __hip_bfloat16* __restrict__ ln_out)
{
    __shared__ float smem[32 * 33];
    int tb = blockIdx.x;
    const int tid = threadIdx.x;

    if (tb >= 12288) {
        // -------- ln1 path
        const int row = tb - 12288;
        const float* xr = x + (size_t)row * 1024;
        const float4 v = *(const float4*)(xr + tid * 4);
        float s  = v.x + v.y + v.z + v.w;
        float s2 = v.x * v.x + v.y * v.y + v.z * v.z + v.w * v.w;
        float* rs  = smem;
        float* rs2 = smem + 256;
        rs[tid] = s; rs2[tid] = s2;
        __syncthreads();
        for (int off = 128; off > 0; off >>= 1) {
            if (tid < off) { rs[tid] += rs[tid + off]; rs2[tid] += rs2[tid + off]; }
            __syncthreads();
        }
        const float mu   = rs[0] * (1.0f / 1024.0f);
        const float var  = rs2[0] * (1.0f / 1024.0f) - mu * mu;
        const float rstd = rsqrtf(var + 1e-5f);
        const float4 w4 = *(const float4*)(ln1_w + tid * 4);
        const float4 b4 = *(const float4*)(ln1_b + tid * 4);
        float o[4] = {(v.x - mu) * rstd * w4.x + b4.x,
                      (v.y - mu) * rstd * w4.y + b4.y,
                      (v.z - mu) * rstd * w4.z + b4.z,
                      (v.w - mu) * rstd * w4.w + b4.w};
        ushort4 pk;
        { __hip_bfloat16 e0 = __float2bfloat16(o[0]); pk.x = *(unsigned short*)&e0;
          __hip_bfloat16 e1 = __float2bfloat16(o[1]); pk.y = *(unsigned short*)&e1;
          __hip_bfloat16 e2 = __float2bfloat16(o[2]); pk.z = *(unsigned short*)&e2;
          __hip_bfloat16 e3 = __float2bfloat16(o[3]); pk.w = *(unsigned short*)&e3; }
        *(ushort4*)(ln_out + (size_t)row * 1024 + tid * 4) = pk;
        return;
    }

    // -------- transpose path (fp32 [K,N] -> bf16 [N,K])
    float (*t)[33] = (float(*)[33])smem;
    const float* W; __hip_bfloat16* Wt; int K, N;
    if (tb < 3072)      { W = attn_w; Wt = attn_wt; K = D_MODEL; N = C3; }
    else if (tb < 4096) { tb -= 3072; W = proj_w; Wt = proj_wt; K = D_MODEL; N = D_MODEL; }
    else if (tb < 8192) { tb -= 4096; W = fc_w;   Wt = fc_wt;   K = D_MODEL; N = D_FF; }
    else                { tb -= 8192; W = fc2_w;  Wt = fc2_wt;  K = D_FF;    N = D_MODEL; }
    const int ntx = N >> 5;
    const int k0 = (tb / ntx) * 32;
    const int n0 = (tb % ntx) * 32;

    const int row = tid >> 3;        // 0..31
    const int c4  = (tid & 7) * 4;   // 0,4,...,28

    const float4 v = *(const float4*)&W[(size_t)(k0 + row) * N + n0 + c4];
    t[row][c4 + 0] = v.x; t[row][c4 + 1] = v.y;
    t[row][c4 + 2] = v.z; t[row][c4 + 3] = v.w;
    __syncthreads();

    ushort4 pk;
    { __hip_bfloat16 e0 = __float2bfloat16(t[c4 + 0][row]); pk.x = *(unsigned short*)&e0;
      __hip_bfloat16 e1 = __float2bfloat16(t[c4 + 1][row]); pk.y = *(unsigned short*)&e1;
      __hip_bfloat16 e2 = __float2bfloat16(t[c4 + 2][row]); pk.z = *(unsigned short*)&e2;
      __hip_bfloat16 e3 = __float2bfloat16(t[c4 + 3][row]); pk.w = *(unsigned short*)&e3; }
    *(ushort4*)&Wt[(size_t)(n0 + row) * K + k0 + c4] = pk;
}

// ----------------------------------------------------------- helpers
__device__ __forceinline__ void async16(const __hip_bfloat16* g, __hip_bfloat16* l)
{
    __builtin_amdgcn_global_load_lds(
        (const __attribute__((address_space(1))) void*)g,
        (__attribute__((address_space(3))) void*)l, 16, 0, 0);
}

__device__ __forceinline__ float gelu_fast(float v)
{
    const float t = v * (0.7978845608f + 0.0356774081f * v * v);
    return v / (1.0f + exp2f(-2.885390082f * t));
}

// XCD-contiguous work remap (T1). All GEMM (x,y)-grids here are %8 == 0.
__device__ __forceinline__ void swz_xcd(int& bx, int& by)
{
    const int nbx = gridDim.x;
    const int nwg = nbx * gridDim.y;
    int lin = blockIdx.y * nbx + blockIdx.x;
    const int per = nwg >> 3;
    lin = (lin & 7) * per + (lin >> 3);   // XCD x -> contiguous work chunk
    bx = lin % nbx;
    by = lin / nbx;
}

// ================= 8-phase 256x256 core (fc1 + qkv) =======================
// (verified R20-R28; ledger: vmcnt(4)@ph1, vmcnt(2)@ph3, floor 2 in
// flight, drain->barrier->read race-free.)

__device__ __forceinline__ void gemm8p_core(
    const __hip_bfloat16* __restrict__ A,
    const __hip_bfloat16* __restrict__ Bt,
    int K, int row0, int col0, f32x4 (&acc)[8][4],
    __hip_bfloat16 (*Asl)[4][64 * 64], __hip_bfloat16 (*Bsl)[2][128 * 64])
{
    const int tid  = threadIdx.x;
    const int wv   = tid >> 6;
    const int lane = tid & 63;
    const int ln15 = lane & 15;
    const int lq   = lane >> 4;
    const int wr   = wv >> 2;
    const int wc   = wv & 3;

    const int srow = tid >> 3;                          // 0..63
    const int sg   = ((tid & 7) ^ ((tid >> 3) & 7)) * 8;  // inv-swizzled src granule
    const __hip_bfloat16* Ab = A  + (size_t)(row0 + srow) * K + sg;
    const __hip_bfloat16* Bb = Bt + (size_t)(col0 + srow) * K + sg;
    const int nt = K >> 6;

#pragma unroll
    for (int mi = 0; mi < 8; ++mi)
#pragma unroll
        for (int ni = 0; ni < 4; ++ni) acc[mi][ni] = (f32x4){0.f, 0.f, 0.f, 0.f};

    auto stA = [&](int t, int buf, int b) {
        async16(Ab + (size_t)(b * 64) * K + t * 64, &Asl[buf][b][0] + tid * 8);
    };
    auto stB = [&](int t, int buf, int h) {
        async16(Bb + (size_t)(h * 128) * K + t * 64, &Bsl[buf][h][0] + tid * 8);
        async16(Bb + (size_t)(h * 128 + 64) * K + t * 64,
                &Bsl[buf][h][0] + 4096 + tid * 8);
    };

    const int rg0 = (lq ^ (ln15 & 7)) * 8;          // kk=0 read granule (elems)
    const int rg1 = ((4 | lq) ^ (ln15 & 7)) * 8;    // kk=1
    auto ldA = [&](int buf, int mi, int kk) -> bf16x8 {
        return *(const bf16x8*)&Asl[buf][wr * 2 + (mi >> 2)]
            [((mi & 3) * 16 + ln15) * 64 + (kk ? rg1 : rg0)];
    };
    auto ldB = [&](int buf, int ni, int kk) -> bf16x8 {
        return *(const bf16x8*)&Bsl[buf][wc >> 1]
            [((wc & 1) * 64 + ni * 16 + ln15) * 64 + (kk ? rg1 : rg0)];
    };

    // prologue: all of tile 0 -> buf 0 (8 loads), drain, join.
    stB(0, 0, 0); stB(0, 0, 1);
    stA(0, 0, 0); stA(0, 0, 2); stA(0, 0, 1); stA(0, 0, 3);
    WAIT_VM0();
    __builtin_amdgcn_s_barrier();

    for (int t = 0; t < nt; ++t) {
        const int pp = t & 1, op = pp ^ 1;
        const int tc = (t + 1 < nt) ? t + 1 : nt - 1;
        bf16x8 af[2][2], bfr[4][2];

        // -------- phase 0: mi 0,1 (+ all B fragment reads, held in regs)
#pragma unroll
        for (int m = 0; m < 2; ++m) { af[m][0] = ldA(pp, m, 0); af[m][1] = ldA(pp, m, 1); }
#pragma unroll
        for (int ni = 0; ni < 4; ++ni) { bfr[ni][0] = ldB(pp, ni, 0); bfr[ni][1] = ldB(pp, ni, 1); }
        stB(tc, op, 0);
        __builtin_amdgcn_s_barrier();
        __builtin_amdgcn_s_setprio(1);
#pragma unroll
        for (int kk = 0; kk < 2; ++kk)
#pragma unroll
            for (int m = 0; m < 2; ++m)
#pragma unroll
                for (int ni = 0; ni < 4; ++ni)
                    acc[m][ni] = __builtin_amdgcn_mfma_f32_16x16x32_bf16(
                        af[m][kk], bfr[ni][kk], acc[m][ni], 0, 0, 0);
        __builtin_amdgcn_s_setprio(0);
        __builtin_amdgcn_s_barrier();

        // -------- phase 1: mi 2,3
#pragma unroll
        for (int m = 0; m < 2; ++m) { af[m][0] = ldA(pp, 2 + m, 0); af[m][1] = ldA(pp, 2 + m, 1); }
        stB(tc, op, 1);
        WAIT_VM4();
        __builtin_amdgcn_s_barrier();
        __builtin_amdgcn_s_setprio(1);
#pragma unroll
        for (int kk = 0; kk < 2; ++kk)
#pragma unroll
            for (int m = 0; m < 2; ++m)
#pragma unroll
                for (int ni = 0; ni < 4; ++ni)
                    acc[2 + m][ni] = __builtin_amdgcn_mfma_f32_16x16x32_bf16(
                        af[m][kk], bfr[ni][kk], acc[2 + m][ni], 0, 0, 0);
        __builtin_amdgcn_s_setprio(0);
        __builtin_amdgcn_s_barrier();

        // -------- phase 2: mi 4,5
#pragma unroll
        for (int m = 0; m < 2; ++m) { af[m][0] = ldA(pp, 4 + m, 0); af[m][1] = ldA(pp, 4 + m, 1); }
        stA(tc, op, 0); stA(tc, op, 2);
        __builtin_amdgcn_s_barrier();
        __builtin_amdgcn_s_setprio(1);
#pragma unroll
        for (int kk = 0; kk < 2; ++kk)
#pragma unroll
            for (int m = 0; m < 2; ++m)
#pragma unroll
                for (int ni = 0; ni < 4; ++ni)
                    acc[4 + m][ni] = __builtin_amdgcn_mfma_f32_16x16x32_bf16(
                        af[m][kk], bfr[ni][kk], acc[4 + m][ni], 0, 0, 0);
        __builtin_amdgcn_s_setprio(0);
        __builtin_amdgcn_s_barrier();

        // -------- phase 3: mi 6,7
#pragma unroll
        for (int m = 0; m < 2; ++m) { af[m][0] = ldA(pp, 6 + m, 0); af[m][1] = ldA(pp, 6 + m, 1); }
        stA(tc, op, 1); stA(tc, op, 3);
        WAIT_VM2();
        __builtin_amdgcn_s_barrier();
        __builtin_amdgcn_s_setprio(1);
#pragma unroll
        for (int kk = 0; kk < 2; ++kk)
#pragma unroll
            for (int m = 0; m < 2; ++m)
#pragma unroll
                for (int ni = 0; ni < 4; ++ni)
                    acc[6 + m][ni] = __builtin_amdgcn_mfma_f32_16x16x32_bf16(
                        af[m][kk], bfr[ni][kk], acc[6 + m][ni], 0, 0, 0);
        __builtin_amdgcn_s_setprio(0);
        __builtin_amdgcn_s_barrier();
    }
}

// ---------------- fc1 kernel (8-phase 256x256, bias+gelu, bf16 out)
__global__ __launch_bounds__(512, 1) void gemm8p_kernel(
    const __hip_bfloat16* __restrict__ A,   // [M,K]
    const __hip_bfloat16* __restrict__ Bt,  // [N,K]
    const float* __restrict__ bias,         // [N]
    __hip_bfloat16* __restrict__ Cout,      // [M,N] bf16
    int M, int N, int K, int act)
{
    __shared__ __align__(16) __hip_bfloat16 Asl[2][4][64 * 64];
    __shared__ __align__(16) __hip_bfloat16 Bsl[2][2][128 * 64];

    int bx, by;
    swz_xcd(bx, by);
    const int row0 = by * 256;
    const int col0 = bx * 256;

    f32x4 acc[8][4];
    gemm8p_core(A, Bt, K, row0, col0, acc, Asl, Bsl);

    const int tid  = threadIdx.x;
    const int wv   = tid >> 6;
    const int lane = tid & 63;
    const int ln15 = lane & 15;
    const int lq   = lane >> 4;
    const int mbase = (wv >> 2) * 128;
    const int nbase = (wv & 3) * 64;

#pragma unroll
    for (int mi = 0; mi < 8; ++mi) {
#pragma unroll
        for (int ni = 0; ni < 4; ++ni) {
            const int gc = col0 + nbase + ni * 16 + ln15;
            const float bv = bias[gc];
#pragma unroll
            for (int r = 0; r < 4; ++r) {
                const int gr = row0 + mbase + mi * 16 + lq * 4 + r;
                float v = acc[mi][ni][r] + bv;
                if (act == 1) v = gelu_fast(v);
                Cout[(size_t)gr * N + gc] = __float2bfloat16(v);
            }
        }
    }
}

// ---------------- qkv kernel (8-phase 256x256) with routing epilogue
__global__ __launch_bounds__(512, 1) void qkv8p_kernel(
    const __hip_bfloat16* __restrict__ A,
    const __hip_bfloat16* __restrict__ Bt,
    const float* __restrict__ bias,
    __hip_bfloat16* __restrict__ Qb,
    __hip_bfloat16* __restrict__ Kb,
    __hip_bfloat16* __restrict__ Vtb)
{
    __shared__ __align__(16) __hip_bfloat16 Asl[2][4][64 * 64];
    __shared__ __align__(16) __hip_bfloat16 Bsl[2][2][128 * 64];

    int bx, by;
    swz_xcd(bx, by);
    const int row0 = by * 256;
    const int col0 = bx * 256;

    f32x4 acc[8][4];
    gemm8p_core(A, Bt, D_MODEL, row0, col0, acc, Asl, Bsl);

    const int tid  = threadIdx.x;
    const int wv   = tid >> 6;
    const int lane = tid & 63;
    const int ln15 = lane & 15;
    const int lq   = lane >> 4;
    const int mbase = (wv >> 2) * 128;
    const int nbase = (wv & 3) * 64;

#pragma unroll
    for (int mi = 0; mi < 8; ++mi) {
        const int gr0 = row0 + mbase + mi * 16 + lq * 4;   // + r
        const int bb  = gr0 >> 11;
        const int q0  = gr0 & 2047;
#pragma unroll
        for (int ni = 0; ni < 4; ++ni) {
            const int gc  = col0 + nbase + ni * 16 + ln15;
            const float bv = bias[gc];
            const int sec = gc >> 10;            // 0:Q 1:K 2:V
            const int hd  = (gc & 1023) >> 6;
            const int d   = gc & 63;
            if (sec == 2) {
                unsigned short u[4];
#pragma unroll
                for (int r = 0; r < 4; ++r) {
                    __hip_bfloat16 e = __float2bfloat16(acc[mi][ni][r] + bv);
                    u[r] = *(unsigned short*)&e;
                }
                uint2 pk;
                pk.x = (unsigned int)u[0] | ((unsigned int)u[1] << 16);
                pk.y = (unsigned int)u[2] | ((unsigned int)u[3] << 16);
                *(uint2*)(Vtb + ((size_t)((bb * N_HEAD + hd) * D_HEAD + d)) * SEQ_T + q0) = pk;
            } else {
                __hip_bfloat16* dst = (sec == 0 ? Qb : Kb)
                    + ((size_t)((bb * N_HEAD + hd) * SEQ_T + q0)) * D_HEAD + d;
#pragma unroll
                for (int r = 0; r < 4; ++r)
                    dst[(size_t)r * D_HEAD] = __float2bfloat16(acc[mi][ni][r] + bv);
            }
        }
    }
}

// ============== GEMM core B: 64x128 tile, BK=64, 3-slot rotation =========
// (verified R27: vmcnt(6) counted drain, 2-tile lead, race-free)
__device__ __forceinline__ void stage_db2w(
    const __hip_bfloat16* __restrict__ Ab, const __hip_bfloat16* __restrict__ Bb,
    int K, int kt, __hip_bfloat16* __restrict__ as,
    __hip_bfloat16* __restrict__ bs, int tid)
{
    const int k0 = kt * 64;
#pragma unroll
    for (int s = 0; s < 2; ++s) {
        async16(Ab + k0 + s * 32, as + s * 64 * 32 + tid * 8);
#pragma unroll
        for (int i = 0; i < 2; ++i)
            async16(Bb + (size_t)(i * 64) * K + k0 + s * 32,
                    bs + s * 128 * 32 + i * 64 * 32 + tid * 8);
    }
}

__device__ __forceinline__ void gemm_db2w(
    const __hip_bfloat16* __restrict__ A,
    const __hip_bfloat16* __restrict__ Bt,
    int K, int row0, int col0, f32x4 (&acc)[2][4])
{
    __shared__ __align__(16) __hip_bfloat16 Asl[3][2 * 64 * 32];    // 24KB
    __shared__ __align__(16) __hip_bfloat16 Bsl[3][2 * 128 * 32];   // 48KB

    const int tid  = threadIdx.x;
    const int wv   = tid >> 6;
    const int lane = tid & 63;
    const int ln15 = lane & 15;
    const int lq   = lane >> 4;
    const int mbase = (wv >> 1) * 32;
    const int nbase = (wv & 1) * 64;
    const int rcol = (lq ^ ((ln15 >> 1) & 3)) * 8;
    const int ssw  = ((tid & 3) ^ ((tid >> 3) & 3)) * 8;
    const __hip_bfloat16* Ab = A  + (size_t)(row0 + (tid >> 2)) * K + ssw;
    const __hip_bfloat16* Bb = Bt + (size_t)(col0 + (tid >> 2)) * K + ssw;
    const int nt = K >> 6;

#pragma unroll
    for (int mi = 0; mi < 2; ++mi)
#pragma unroll
        for (int ni = 0; ni < 4; ++ni) acc[mi][ni] = (f32x4){0.f, 0.f, 0.f, 0.f};

    // prologue: tiles 0,1 -> slots 0,1 (12 loads); drain tile 0; join.
    stage_db2w(Ab, Bb, K, 0, &Asl[0][0], &Bsl[0][0], tid);
    stage_db2w(Ab, Bb, K, 1, &Asl[1][0], &Bsl[1][0], tid);
    WAIT_VM6();
    __builtin_amdgcn_s_barrier();

    for (int t = 0; t < nt; ++t) {
        const int p   = t % 3;
        const int p2  = (t + 2) % 3;
        const int tcl = (t + 2 < nt) ? t + 2 : nt - 1;
        bf16x8 af[2][2], bfr[2][4];

#pragma unroll
        for (int s = 0; s < 2; ++s) {
#pragma unroll
            for (int mi = 0; mi < 2; ++mi)
                af[s][mi] = *(const bf16x8*)
                    &Asl[p][s * 64 * 32 + (mbase + mi * 16 + ln15) * 32 + rcol];
#pragma unroll
            for (int ni = 0; ni < 4; ++ni)
                bfr[s][ni] = *(const bf16x8*)
                    &Bsl[p][s * 128 * 32 + (nbase + ni * 16 + ln15) * 32 + rcol];
        }

        stage_db2w(Ab, Bb, K, tcl, &Asl[p2][0], &Bsl[p2][0], tid);

        WAIT_VM6();                     // drain tile t+1; t+2 stays in flight
        __builtin_amdgcn_s_barrier();   // all waves: tile t+1 ready

        __builtin_amdgcn_s_setprio(1);
#pragma unroll
        for (int s = 0; s < 2; ++s)
#pragma unroll
            for (int mi = 0; mi < 2; ++mi)
#pragma unroll
                for (int ni = 0; ni < 4; ++ni)
                    acc[mi][ni] = __builtin_amdgcn_mfma_f32_16x16x32_bf16(
                        af[s][mi], bfr[s][ni], acc[mi][ni], 0, 0, 0);
        __builtin_amdgcn_s_setprio(0);
    }
}

// ---------------- 64x128 BK=64 kernel (proj, fc2)
__global__ __launch_bounds__(256, 2) void gemm64_kernel(
    const __hip_bfloat16* __restrict__ A,
    const __hip_bfloat16* __restrict__ Bt,
    const float* __restrict__ bias,
    const float* __restrict__ residual,
    void* __restrict__ Cout,
    int M, int N, int K, int act, int outBf16)
{
    int bx, by;
    swz_xcd(bx, by);
    const int row0 = by * 64;
    const int col0 = bx * 128;

    f32x4 acc[2][4];
    gemm_db2w(A, Bt, K, row0, col0, acc);

    const int tid  = threadIdx.x;
    const int wv   = tid >> 6;
    const int lane = tid & 63;
    const int ln15 = lane & 15;
    const int lq   = lane >> 4;
    const int mbase = (wv >> 1) * 32;
    const int nbase = (wv & 1) * 64;

#pragma unroll
    for (int mi = 0; mi < 2; ++mi) {
#pragma unroll
        for (int ni = 0; ni < 4; ++ni) {
            const int gc = col0 + nbase + ni * 16 + ln15;
            const float bv = bias[gc];
#pragma unroll
            for (int r = 0; r < 4; ++r) {
                const int gr = row0 + mbase + mi * 16 + lq * 4 + r;
                float v = acc[mi][ni][r] + bv;
                if (act == 1) v = gelu_fast(v);
                if (residual) v += residual[(size_t)gr * N + gc];
                if (outBf16)
                    ((__hip_bfloat16*)Cout)[(size_t)gr * N + gc] = __float2bfloat16(v);
                else
                    ((float*)Cout)[(size_t)gr * N + gc] = v;
            }
        }
    }
}

// ------------------------------------------------ MFMA flash attention v10
// v9 staging (K via global_load_lds, gemm8p swizzle; V reg-staged padded;
// one barrier/tile; paired; head-locality; defer-max) + softmax dependency
// chains broken into 4 parallel per-r partials (fmax and psum).
#define ATQ 64
#define ATK 128
#define NQT (SEQ_T / ATQ)   // 32
#define VP2 136             // Vts row stride (elems)

__global__ __launch_bounds__(256) void mfma_attn_kernel(
    const __hip_bfloat16* __restrict__ Qb,
    const __hip_bfloat16* __restrict__ Kb,
    const __hip_bfloat16* __restrict__ Vtb,
    __hip_bfloat16* __restrict__ y)
{
    __shared__ __align__(16) __hip_bfloat16 Ks[2][ATK * 64];    // [buf][j][d] swz; buf0 = O-scratch
    __shared__ __align__(16) __hip_bfloat16 Vts[2][D_HEAD * VP2];

    const int flat = (blockIdx.z * gridDim.y + blockIdx.y) * gridDim.x + blockIdx.x;
    const int xcd  = flat & 7;
    const int slot = flat >> 3;
    const int pair = slot & 15;          // 0..15
    const int hb   = slot >> 4;          // 0..3
    const int h    = xcd + 8 * (hb & 1);
    const int b    = hb >> 1;

    const int tid  = threadIdx.x;
    const int wv   = tid >> 6;
    const int lane = tid & 63;
    const int ln15 = lane & 15;
    const int lq   = lane >> 4;

    const __hip_bfloat16* Qh = Qb  + (size_t)(b * N_HEAD + h) * SEQ_T * D_HEAD;
    const __hip_bfloat16* Kh = Kb  + (size_t)(b * N_HEAD + h) * SEQ_T * D_HEAD;
    const __hip_bfloat16* Vh = Vtb + (size_t)(b * N_HEAD + h) * D_HEAD * SEQ_T;
    const size_t bT = (size_t)b * SEQ_T;

    const float CEXP = 0.18033688011f;   // 0.125 * log2(e)
    const float DTHR = 8.0f / CEXP;      // defer-max threshold, raw-score units

    // K staging: lane (kr,kg); gemm8p source swizzle kg^(kr&7); dest linear.
    const int kr  = tid >> 3, kg = tid & 7;
    const int ksg = (kg ^ (kr & 7)) * 8;
    // V staging regs
    bf16x8 vreg[4];
    const int vr = tid >> 4, vc = tid & 15;

    auto issueK = [&](int kb, int buf) {
#pragma unroll
        for (int i = 0; i < 4; ++i)
            async16(Kh + (size_t)(kb + kr + i * 32) * D_HEAD + ksg,
                    &Ks[buf][i * 2048] + tid * 8);
    };
    auto issueV = [&](int kb) {
#pragma unroll
        for (int i = 0; i < 4; ++i)
            vreg[i] = *(const bf16x8*)(Vh + (size_t)(vr + i * 16) * SEQ_T + kb + vc * 8);
    };
    auto commitV = [&](int buf) {
#pragma unroll
        for (int i = 0; i < 4; ++i)
            *(bf16x8*)&Vts[buf][(vr + i * 16) * VP2 + vc * 8] = vreg[i];
    };

    // QK^T read granules (gemm8p pattern; row = jf*16+ln15)
    const int rg0 = (lq ^ (ln15 & 7)) * 8;
    const int rg1 = ((4 | lq) ^ (ln15 & 7)) * 8;

#pragma unroll 1
    for (int half = 0; half < 2; ++half) {
        const int qt    = half == 0 ? pair : (NQT - 1 - pair);
        const int qbase = qt * ATQ;
        const int ntk   = (qt >> 1) + 1;
        const int qg    = qbase + wv * 16 + ln15;   // stats-owner q row

        bf16x8 qf[2];
#pragma unroll
        for (int kc = 0; kc < 2; ++kc)
            qf[kc] = *(const bf16x8*)(Qh + (size_t)(qbase + wv * 16 + ln15) * D_HEAD
                                      + kc * 32 + lq * 8);

        f32x4 Oacc[4];
#pragma unroll
        for (int dn = 0; dn < 4; ++dn) Oacc[dn] = (f32x4){0.f, 0.f, 0.f, 0.f};
        float m_run = -INFINITY, l_run = 0.f;

        issueK(0, 0);     // K gloads FIRST (so V's drain covers them)
        issueV(0);

        for (int t = 0; t < ntk; ++t) {
            const int kb  = t * ATK;
            const int buf = t & 1;
            commitV(buf);               // implicit vmcnt wait drains V(t)+K(t)
            __syncthreads();            // all waves' tile-t data in LDS
            if (t + 1 < ntk) {          // prefetch t+1 under compute of t
                issueK((t + 1) * ATK, buf ^ 1);
                issueV((t + 1) * ATK);
            }

            // ---- S^T[j=128][q=16] : A=K (rows j), B=Q (rows q), 16x16x32
            f32x4 st[8];
#pragma unroll
            for (int jf = 0; jf < 8; ++jf) st[jf] = (f32x4){0.f, 0.f, 0.f, 0.f};
            __builtin_amdgcn_s_setprio(1);
#pragma unroll
            for (int jf = 0; jf < 8; ++jf) {
                const int rw = jf * 16 + ln15;
                const bf16x8 kf0 = *(const bf16x8*)&Ks[buf][rw * 64 + rg0];
                const bf16x8 kf1 = *(const bf16x8*)&Ks[buf][rw * 64 + rg1];
                st[jf] = __builtin_amdgcn_mfma_f32_16x16x32_bf16(kf0, qf[0], st[jf], 0, 0, 0);
                st[jf] = __builtin_amdgcn_mfma_f32_16x16x32_bf16(kf1, qf[1], st[jf], 0, 0, 0);
            }
            __builtin_amdgcn_s_setprio(0);

            // ---- causal mask on the diagonal tile (raw-score domain)
            if (t == ntk - 1) {
#pragma unroll
                for (int jf = 0; jf < 8; ++jf)
#pragma unroll
                    for (int r = 0; r < 4; ++r)
                        if ((kb + jf * 16 + lq * 4 + r) > qg) st[jf][r] = -INFINITY;
            }

            // ---- online softmax; 4 parallel per-r chains (latency break)
            float tm0 = st[0][0], tm1 = st[0][1], tm2 = st[0][2], tm3 = st[0][3];
#pragma unroll
            for (int jf = 1; jf < 8; ++jf) {
                tm0 = fmaxf(tm0, st[jf][0]);
                tm1 = fmaxf(tm1, st[jf][1]);
                tm2 = fmaxf(tm2, st[jf][2]);
                tm3 = fmaxf(tm3, st[jf][3]);
            }
            float tmax = fmaxf(fmaxf(tm0, tm1), fmaxf(tm2, tm3));
            tmax = fmaxf(tmax, __shfl_xor(tmax, 16));
            tmax = fmaxf(tmax, __shfl_xor(tmax, 32));

            if (!__all(tmax <= m_run + DTHR)) {
                const float mnew  = fmaxf(m_run, tmax);
                const float alpha = exp2f((m_run - mnew) * CEXP);
                l_run *= alpha;
                m_run = mnew;
                float a4[4];
#pragma unroll
                for (int r = 0; r < 4; ++r) a4[r] = __shfl(alpha, lq * 4 + r);
#pragma unroll
                for (int dn = 0; dn < 4; ++dn)
#pragma unroll
                    for (int r = 0; r < 4; ++r) Oacc[dn][r] *= a4[r];
            }
            const float mc = m_run * CEXP;
            float ps0 = 0.f, ps1 = 0.f, ps2 = 0.f, ps3 = 0.f;
#pragma unroll
            for (int jf = 0; jf < 8; ++jf) {
                const float p0 = exp2f(fmaf(st[jf][0], CEXP, -mc));
                const float p1 = exp2f(fmaf(st[jf][1], CEXP, -mc));
                const float p2 = exp2f(fmaf(st[jf][2], CEXP, -mc));
                const float p3 = exp2f(fmaf(st[jf][3], CEXP, -mc));
                st[jf][0] = p0; st[jf][1] = p1; st[jf][2] = p2; st[jf][3] = p3;
                ps0 += p0; ps1 += p1; ps2 += p2; ps3 += p3;
            }
            float psum = (ps0 + ps1) + (ps2 + ps3);
            psum += __shfl_xor(psum, 16);
            psum += __shfl_xor(psum, 32);
            l_run += psum;

            // ---- O += P V via 16x16x16: P-frag is the S^T C-fragment
            __builtin_amdgcn_s_setprio(1);
#pragma unroll
            for (int jf = 0; jf < 8; ++jf) {
                s16x4 pfr;
#pragma unroll
                for (int s = 0; s < 4; ++s) {
                    __hip_bfloat16 e = __float2bfloat16(st[jf][s]);
                    pfr[s] = __builtin_bit_cast(short, e);
                }
#pragma unroll
                for (int dn = 0; dn < 4; ++dn) {
                    const s16x4 vfr = *(const s16x4*)&Vts[buf][(dn * 16 + ln15) * VP2
                                                            + jf * 16 + lq * 4];
                    Oacc[dn] = mfma16_bf16(pfr, vfr, Oacc[dn]);
                }
            }
            __builtin_amdgcn_s_setprio(0);
            // no trailing barrier: next iter's writes target the other
            // buffer, whose reads completed before THIS iter's barrier.
        }

        // ---- epilogue: all compute reads done before Ks[0] scratch reuse
        __syncthreads();
        float il[4];
#pragma unroll
        for (int r = 0; r < 4; ++r) il[r] = 1.0f / __shfl(l_run, lq * 4 + r);
#pragma unroll
        for (int dn = 0; dn < 4; ++dn)
#pragma unroll
            for (int r = 0; r < 4; ++r)
                Ks[0][(wv * 16 + lq * 4 + r) * 72 + dn * 16 + ln15] =
                    __float2bfloat16(Oacc[dn][r] * il[r]);
        __syncthreads();
        const int r2 = lane >> 3, c8 = (lane & 7) * 8;
#pragma unroll
        for (int i = 0; i < 2; ++i) {
            const int row = wv * 16 + r2 + 8 * i;
            const bf16x8 val = *(const bf16x8*)&Ks[0][row * 72 + c8];
            *(bf16x8*)(y + (bT + qbase + row) * D_MODEL + h * D_HEAD + c8) = val;
        }
        __syncthreads();                // scratch free before next half
    }
}

// ------------------------------------------------------------------ launch
extern "C" void kernel_launch(void* const* d_in, const int* in_sizes, int n_in,
                              void* d_out, int out_size, void* d_ws, size_t ws_size,
                              hipStream_t stream)
{
    const float* x      = (const float*)d_in[0];
    const float* ln1_w  = (const float*)d_in[1];
    const float* ln1_b  = (const float*)d_in[2];
    const float* attn_w = (const float*)d_in[3];
    const float* attn_b = (const float*)d_in[4];
    const float* proj_w = (const float*)d_in[5];
    const float* proj_b = (const float*)d_in[6];
    const float* ln2_w  = (const float*)d_in[7];
    const float* ln2_b  = (const float*)d_in[8];
    const float* fc_w   = (const float*)d_in[9];
    const float* fc_b   = (const float*)d_in[10];
    const float* fc2_w  = (const float*)d_in[11];
    const float* fc2_b  = (const float*)d_in[12];
    float* out = (float*)d_out;

    char* ws = (char*)d_ws;
    __hip_bfloat16* Qb      = (__hip_bfloat16*)(ws);
    __hip_bfloat16* Kb      = (__hip_bfloat16*)(ws + (size_t)8  * 1024 * 1024);
    __hip_bfloat16* Vtb     = (__hip_bfloat16*)(ws + (size_t)16 * 1024 * 1024);
    __hip_bfloat16* h_bf    = (__hip_bfloat16*)(ws);
    __hip_bfloat16* ln_buf  = (__hip_bfloat16*)(ws + (size_t)32 * 1024 * 1024);
    __hip_bfloat16* y_buf   = (__hip_bfloat16*)(ws + (size_t)40 * 1024 * 1024);
    float*          xmid    = (float*)(ws + (size_t)48 * 1024 * 1024);
    __hip_bfloat16* attn_wt = (__hip_bfloat16*)(ws + (size_t)64 * 1024 * 1024);
    __hip_bfloat16* proj_wt = (__hip_bfloat16*)(ws + (size_t)70 * 1024 * 1024);
    __hip_bfloat16* fc_wt   = (__hip_bfloat16*)(ws + (size_t)72 * 1024 * 1024);
    __hip_bfloat16* fc2_wt  = (__hip_bfloat16*)(ws + (size_t)80 * 1024 * 1024);

    dim3 blk256(256);
    dim3 blk512(512);

    // 0. fused prep: all weight transposes + ln1(x) in one launch
    prep_kernel<<<dim3(12288 + NROWS), blk256, 0, stream>>>(
        attn_w, proj_w, fc_w, fc2_w, attn_wt, proj_wt, fc_wt, fc2_wt,
        x, ln1_w, ln1_b, ln_buf);

    // 1. qkv GEMM (8-phase 256x256) -> Qb/Kb/Vtb   grid 12x16 = 192
    qkv8p_kernel<<<dim3(C3 / 256, NROWS / 256), blk512, 0, stream>>>(
        ln_buf, attn_wt, attn_b, Qb, Kb, Vtb);

    // 2. MFMA flash attention v10 -> y_buf (bf16)
    mfma_attn_kernel<<<dim3(NQT / 2, N_HEAD, BATCH), blk256, 0, stream>>>(
        Qb, Kb, Vtb, y_buf);

    // 3. xmid = x + y_buf @ proj_w + proj_b  (fp32, 3-slot 64x128, grid 512)
    gemm64_kernel<<<dim3(D_MODEL / 128, NROWS / 64), blk256, 0, stream>>>(
        y_buf, proj_wt, proj_b, x, xmid, NROWS, D_MODEL, D_MODEL, 0, 0);

    // 4. ln2(xmid) -> ln_buf (bf16)
    ln_kernel<<<dim3(NROWS), blk256, 0, stream>>>(xmid, ln2_w, ln2_b, ln_buf, D_MODEL);

    // 5. h = gelu(ln_buf @ fc_w + fc_b) -> bf16 (8-phase 256x256, grid 256)
    gemm8p_kernel<<<dim3(D_FF / 256, NROWS / 256), blk512, 0, stream>>>(
        ln_buf, fc_wt, fc_b, h_bf, NROWS, D_FF, D_MODEL, 1);

    // 6. out = xmid + h @ fc2_w + fc2_b  (fp32, 3-slot 64x128, grid 512)
    gemm64_kernel<<<dim3(D_MODEL / 128, NROWS / 64), blk256, 0, stream>>>(
        h_bf, fc2_wt, fc2_b, xmid, out, NROWS, D_MODEL, D_FF, 0, 0);
}